// Round 11
// baseline (245.533 us; speedup 1.0000x reference)
//
#include <hip/hip_runtime.h>
#include <hip/hip_fp16.h>
#include <math.h>

#define N_NODES 50000
#define N_RELS  500
#define N_EDGE  800000
#define HID     64
#define HEADS   4
#define DH      16
#define LAYERS  2
#define HOPS    3
#define TOPK    10
#define ALPHA   0.15f
#define SLOPE   0.2f

#define NBUCK 128
#define DST_PER_BUCK 391    // 128*391 = 50048 >= 50000
#define BUCK_CAP 8192       // mean 6256, sigma ~79 -> ~24 sigma margin
#define L1_EDGES 4096
#define L1_NBLK ((N_EDGE + L1_EDGES - 1) / L1_EDGES)   // 196

typedef unsigned long long u64;
typedef unsigned int u32;

// pack layout: [eid:20 (42..61) | dst:16 (26..41) | rel:10 (16..25) | src:16 (0..15)]
#define PK_SRC(p)  ((int)((p) & 0xFFFF))
#define PK_REL(p)  ((int)(((p) >> 16) & 0x3FF))
#define PK_DST(p)  ((int)(((p) >> 26) & 0xFFFF))
#define PK_EID(p)  ((int)((p) >> 42))

#define NEGI (-3.4e38f)

// monotone float -> u32 (order-preserving), and exact inverse
__device__ __forceinline__ unsigned ordf(float s) {
    unsigned u = __float_as_uint(s);
    return u ^ (0x80000000u | (unsigned)((int)u >> 31));
}
__device__ __forceinline__ float unordf(unsigned o) {
    unsigned u = (o & 0x80000000u) ? (o ^ 0x80000000u) : ~o;
    return __uint_as_float(u);
}

// fp16 row helpers: row = 64 halves (128 B); o4 indexes 8 B fp16 quads
__device__ __forceinline__ float4 load16(const __half* base, size_t o4) {
    float2 rv = *(const float2*)(base + o4 * 4);
    __half2 h0 = *(__half2*)&rv.x;
    __half2 h1 = *(__half2*)&rv.y;
    float2 f0 = __half22float2(h0);
    float2 f1 = __half22float2(h1);
    return make_float4(f0.x, f0.y, f1.x, f1.y);
}
__device__ __forceinline__ void store16(__half* base, size_t o4, float4 v) {
    __half2 h0 = __floats2half2_rn(v.x, v.y);
    __half2 h1 = __floats2half2_rn(v.z, v.w);
    float2 rv;
    *(__half2*)&rv.x = h0;
    *(__half2*)&rv.y = h1;
    *(float2*)(base + o4 * 4) = rv;
}

// ---------------------------------------------------------------- rel_all: relout + s_rel (both layers) + bcur zero
__global__ void rel_all(const float* __restrict__ rel_emb, const float* __restrict__ W_rel,
                        const float* __restrict__ attn_a, const float* __restrict__ fc_rel_w,
                        float* __restrict__ s_rel, float* __restrict__ out_hr,
                        int* __restrict__ bcur) {
    __shared__ float proj[64];
    int b = blockIdx.x, c = threadIdx.x;   // 1500 x 64
    if (b == 0) for (int i = c; i < NBUCK; i += 64) bcur[i] = 0;
    int mode = b / N_RELS;                 // 0=relout, 1=layer0 s_rel, 2=layer1 s_rel
    int r = b - mode * N_RELS;
    const float* W = (mode == 0) ? fc_rel_w : (W_rel + (size_t)(mode - 1) * HID * HID);
    float acc = 0.f;
    #pragma unroll
    for (int k = 0; k < 64; ++k) acc += rel_emb[(size_t)r * 64 + k] * W[k * 64 + c];
    if (mode == 0) { out_hr[(size_t)r * 64 + c] = acc; return; }
    proj[c] = acc;
    __syncthreads();
    if (c < HEADS) {
        const float* a2 = attn_a + (size_t)(mode - 1) * 3 * HEADS * DH + 2 * HEADS * DH;
        float s = 0.f;
        #pragma unroll
        for (int d = 0; d < 16; ++d) s += proj[c * 16 + d] * a2[c * 16 + d];
        s_rel[(size_t)(mode - 1) * N_RELS * HEADS + r * HEADS + c] = s;
    }
}

// ---------------------------------------------------------------- level-1: bucket stage (no global hist)
__global__ __launch_bounds__(1024) void bucket_scatter_l1(
        const int* __restrict__ src, const int* __restrict__ dst, const int* __restrict__ rel,
        int* __restrict__ bcur, u64* __restrict__ staging) {
    __shared__ u64 buf[L1_EDGES];
    __shared__ unsigned char bb[L1_EDGES];
    __shared__ int hist[NBUCK], lstart[NBUCK], cur[NBUCK], delta[NBUCK];
    __shared__ int wtot[2];
    int t = threadIdx.x;
    int e0 = blockIdx.x * L1_EDGES;
    if (t < NBUCK) hist[t] = 0;
    __syncthreads();

    u64 myp[4]; int myb[4]; bool mv[4];
    #pragma unroll
    for (int q = 0; q < 4; ++q) {
        int e = e0 + q * 1024 + t;
        mv[q] = (e < N_EDGE);
        if (mv[q]) {
            int d = dst[e];
            int b = d / DST_PER_BUCK;
            myp[q] = ((u64)(unsigned)e << 42) | ((u64)(unsigned)d << 26)
                   | ((unsigned)rel[e] << 16) | (unsigned)src[e];
            myb[q] = b;
            atomicAdd(&hist[b], 1);
        }
    }
    __syncthreads();
    int inc = 0;
    if (t < NBUCK) {       // two-wave exclusive scan over 128 hist entries
        int v = hist[t];
        int lane = t & 63;
        inc = v;
        #pragma unroll
        for (int off = 1; off < 64; off <<= 1) {
            int u = __shfl_up(inc, off, 64);
            if (lane >= off) inc += u;
        }
        if (lane == 63) wtot[t >> 6] = inc;
    }
    __syncthreads();
    if (t < NBUCK) {
        int base = (t >= 64) ? wtot[0] : 0;
        int excl = base + inc - hist[t];
        lstart[t] = excl;
        cur[t] = excl;
    }
    __syncthreads();
    #pragma unroll
    for (int q = 0; q < 4; ++q) {
        if (mv[q]) {
            int lp = atomicAdd(&cur[myb[q]], 1);
            buf[lp] = myp[q];
            bb[lp] = (unsigned char)myb[q];
        }
    }
    __syncthreads();
    if (t < NBUCK && hist[t] > 0) {
        int g = atomicAdd(&bcur[t], hist[t]);
        delta[t] = t * BUCK_CAP + g - lstart[t];
    }
    __syncthreads();
    int total = N_EDGE - e0; if (total > L1_EDGES) total = L1_EDGES;
    for (int i = t; i < total; i += 1024) {
        staging[(size_t)(delta[bb[i]] + i)] = buf[i];
    }
}

// ---------------------------------------------------------------- level-2: per-bucket hist + scan + row_ptr + place
__global__ __launch_bounds__(1024) void bucket_scatter_l2(
        const u64* __restrict__ staging, const int* __restrict__ bcur,
        int* __restrict__ row_ptr, u64* __restrict__ sorted_pack) {
    __shared__ int hist[DST_PER_BUCK];
    __shared__ int cur[DST_PER_BUCK];
    __shared__ int sc[512];
    __shared__ int base_sh;
    int b = blockIdx.x, t = threadIdx.x;
    int d0 = b * DST_PER_BUCK;
    int d1 = d0 + DST_PER_BUCK; if (d1 > N_NODES) d1 = N_NODES;
    int nd = d1 - d0;
    if (t < DST_PER_BUCK) hist[t] = 0;
    if (t < 64) {          // base = sum bcur[0..b-1]
        int s = 0;
        if (t < b) s += bcur[t];
        if (t + 64 < b) s += bcur[t + 64];
        #pragma unroll
        for (int off = 32; off > 0; off >>= 1) s += __shfl_down(s, off, 64);
        if (t == 0) base_sh = s;
    }
    int cnt_b = bcur[b];
    size_t sbase = (size_t)b * BUCK_CAP;
    __syncthreads();
    for (int j = t; j < cnt_b; j += 1024) {              // pass 1: histogram
        u64 p = staging[sbase + j];
        atomicAdd(&hist[PK_DST(p) - d0], 1);
    }
    __syncthreads();
    if (t < 512) sc[t] = (t < nd) ? hist[t] : 0;
    __syncthreads();
    #pragma unroll
    for (int off = 1; off < 512; off <<= 1) {            // Hillis-Steele inclusive scan
        int v = (t < 512 && t >= off) ? sc[t - off] : 0;
        __syncthreads();
        if (t < 512) sc[t] += v;
        __syncthreads();
    }
    if (t < nd) {
        int excl = base_sh + sc[t] - hist[t];
        cur[t] = excl;
        row_ptr[d0 + t] = excl;
    }
    if (b == NBUCK - 1 && t == 0) row_ptr[N_NODES] = N_EDGE;
    __syncthreads();
    for (int j = t; j < cnt_b; j += 1024) {              // pass 2: place (L2-hot)
        u64 p = staging[sbase + j];
        int pos = atomicAdd(&cur[PK_DST(p) - d0], 1);
        sorted_pack[pos] = p;
    }
}

// ---------------------------------------------------------------- dense: dual GEMM + score epilogue
__global__ __launch_bounds__(256) void gemm_dual(
        const float* __restrict__ A, const float* __restrict__ W1, const float* __restrict__ W2,
        const float* __restrict__ a_vec,
        __half* __restrict__ C1h, float* __restrict__ C2,
        float* __restrict__ s_src, float* __restrict__ s_dst, int n) {
    __shared__ float W1s[64][64];   // [k][c]
    __shared__ float W2s[64][64];
    __shared__ float As[32][64];
    __shared__ float a_sh[128];
    int t = threadIdx.x;      // 256
    const float4* W1v = (const float4*)W1;
    const float4* W2v = (const float4*)W2;
    for (int i = t; i < 1024; i += 256) {
        ((float4*)W1s)[i] = W1v[i];
        ((float4*)W2s)[i] = W2v[i];
    }
    if (t < 128) a_sh[t] = a_vec[t];
    int row0 = blockIdx.x * 32;
    const float4* Av = (const float4*)A;
    for (int i = t; i < 512; i += 256) {
        int gr = row0 + (i >> 4);
        ((float4*)As)[i] = (gr < n) ? Av[(size_t)row0 * 16 + i] : make_float4(0.f, 0.f, 0.f, 0.f);
    }
    __syncthreads();
    int cq = (t & 15) * 4;
    int rs = t >> 4;
    float4 a1a = make_float4(0.f,0.f,0.f,0.f), a1b = a1a, a2a = a1a, a2b = a1a;
    #pragma unroll 4
    for (int k = 0; k < 64; ++k) {
        float va = As[rs][k];
        float vb = As[rs + 16][k];
        float4 w1 = *(const float4*)&W1s[k][cq];
        float4 w2 = *(const float4*)&W2s[k][cq];
        a1a.x += va * w1.x; a1a.y += va * w1.y; a1a.z += va * w1.z; a1a.w += va * w1.w;
        a2a.x += va * w2.x; a2a.y += va * w2.y; a2a.z += va * w2.z; a2a.w += va * w2.w;
        a1b.x += vb * w1.x; a1b.y += vb * w1.y; a1b.z += vb * w1.z; a1b.w += vb * w1.w;
        a2b.x += vb * w2.x; a2b.y += vb * w2.y; a2b.z += vb * w2.z; a2b.w += vb * w2.w;
    }
    int gra = row0 + rs, grb = row0 + rs + 16;
    if (gra < n) {
        store16(C1h, (size_t)gra * 16 + (t & 15), a1a);
        *(float4*)&C2[(size_t)gra * 64 + cq] = a2a;
    }
    if (grb < n) {
        store16(C1h, (size_t)grb * 16 + (t & 15), a1b);
        *(float4*)&C2[(size_t)grb * 64 + cq] = a2b;
    }
    __syncthreads();
    *(float4*)&As[rs][cq]      = a1a;      // park fp32 C1 tile for score epilogue
    *(float4*)&As[rs + 16][cq] = a1b;
    __syncthreads();
    if (t < 128) {
        int nl = t >> 2, h = t & 3;
        int gr = row0 + nl;
        if (gr < n) {
            float ss = 0.f, sd = 0.f;
            #pragma unroll
            for (int d = 0; d < 16; ++d) {
                float v = As[nl][h * 16 + d];
                ss += v * a_sh[h * 16 + d];
                sd += v * a_sh[64 + h * 16 + d];
            }
            s_src[gr * 4 + h] = ss;
            s_dst[gr * 4 + h] = sd;
        }
    }
}

// ---------------------------------------------------------------- edge scores (head-major planes)
__global__ void edge_scores(const u64* __restrict__ pack, const float* __restrict__ s_src,
                            const float* __restrict__ s_rel, float* __restrict__ sc) {
    int j = blockIdx.x * 256 + threadIdx.x;
    if (j >= N_EDGE) return;
    u64 p = pack[j];
    int src = PK_SRC(p);
    int rel = PK_REL(p);
    float4 a = *(const float4*)(s_src + (size_t)src * 4);
    float4 b = *(const float4*)(s_rel + (size_t)rel * 4);
    sc[0 * N_EDGE + j] = a.x + b.x;
    sc[1 * N_EDGE + j] = a.y + b.y;
    sc[2 * N_EDGE + j] = a.z + b.z;
    sc[3 * N_EDGE + j] = a.w + b.w;
}

// ---------------------------------------------------------------- top-k (u64-key, 2 threads per dst, head = blockIdx.y)
// plane-major: a wave's 64 lanes cover 32 consecutive dst in ONE head plane -> coalesced batches.
__global__ void topk_kernel(const int* __restrict__ row_ptr, const u64* __restrict__ pack,
                            const float* __restrict__ sc_all, const float* __restrict__ s_dst,
                            u32* __restrict__ kept) {
    int tid = blockIdx.x * 256 + threadIdx.x;
    int d = tid >> 1;                 // dst node
    if (d >= N_NODES) return;
    int q = tid & 1;                  // which half of the segment
    int h = blockIdx.y;
    int t = d * HEADS + h;            // output index
    int beg = row_ptr[d], end = row_ptr[d + 1];
    const float* sc = sc_all + (size_t)h * N_EDGE;

    u64 topK[TOPK]; int topN[TOPK];
    #pragma unroll
    for (int i = 0; i < TOPK; ++i) { topK[i] = 0ull; topN[i] = 0; }
    float thr9 = unordf(0u);   // -NaN: comparisons false -> nothing rejected while filling

    auto ins = [&](float s, int j) {
        if (s < thr9) return;                       // NaN-safe: false while unfilled
        u64 p = pack[j];
        unsigned eid = (unsigned)PK_EID(p);
        u64 key = ((u64)ordf(s) << 20) | (u64)(0xFFFFFu - eid);
        if (key <= topK[TOPK - 1]) return;
        int sn = PK_SRC(p);
        #pragma unroll
        for (int i = 0; i < TOPK; ++i) {
            bool b = key > topK[i];
            u64 tk = topK[i]; int tn = topN[i];
            topK[i] = b ? key : tk;  topN[i] = b ? sn : tn;
            key     = b ? tk : key;  sn      = b ? tn : sn;
        }
        thr9 = unordf((unsigned)(topK[TOPK - 1] >> 20));
    };

    for (int j = (beg & ~3) + (q << 2); j < end; j += 8) {   // interleaved aligned batches
        float4 v = *(const float4*)(sc + j);
        float s0 = (j     >= beg)                ? v.x : NEGI;
        float s1 = (j + 1 >= beg && j + 1 < end) ? v.y : NEGI;
        float s2 = (j + 2 >= beg && j + 2 < end) ? v.z : NEGI;
        float s3 = (j + 3 < end)                 ? v.w : NEGI;
        float mx = fmaxf(fmaxf(s0, s1), fmaxf(s2, s3));
        if (mx < thr9) continue;
        ins(s0, j); ins(s1, j + 1); ins(s2, j + 2); ins(s3, j + 3);
    }

    // merge partner's sorted list (adjacent lane, disjoint edges -> distinct keys)
    u64 ok[TOPK]; int on[TOPK];
    #pragma unroll
    for (int i = 0; i < TOPK; ++i) {
        unsigned lo = (unsigned)__shfl_xor((int)(topK[i] & 0xFFFFFFFFull), 1, 64);
        unsigned hi = (unsigned)__shfl_xor((int)(topK[i] >> 32), 1, 64);
        ok[i] = ((u64)hi << 32) | lo;
        on[i] = __shfl_xor(topN[i], 1, 64);
    }
    for (int i = 0; i < TOPK; ++i) {
        u64 key = ok[i]; int sn = on[i];
        if (key <= topK[TOPK - 1]) break;          // rest are smaller: can't enter top-10
        #pragma unroll
        for (int ii = 0; ii < TOPK; ++ii) {
            bool b = key > topK[ii];
            u64 tk = topK[ii]; int tn = topN[ii];
            topK[ii] = b ? key : tk;  topN[ii] = b ? sn : tn;
            key      = b ? tk : key;  sn       = b ? tn : sn;
        }
    }
    if (q) return;                                 // both lanes hold identical merged lists

    int deg = end - beg;
    int cnt = deg < TOPK ? deg : TOPK;
    float sdst = s_dst[t];
    float tm = unordf((unsigned)(topK[0] >> 20)) + sdst;
    tm = tm > 0.f ? tm : SLOPE * tm;
    float w[TOPK]; float den = 0.f;
    #pragma unroll
    for (int i = 0; i < TOPK; ++i) {
        float ti = unordf((unsigned)(topK[i] >> 20)) + sdst;
        ti = ti > 0.f ? ti : SLOPE * ti;
        float e = (i < cnt) ? expf(ti - tm) : 0.f;
        w[i] = e; den += e;
    }
    float inv = 1.f / (den + 1e-16f);
    #pragma unroll
    for (int i = 0; i < TOPK; ++i) {
        float wv = (i < cnt) ? w[i] * inv : 0.f;
        kept[(size_t)t * TOPK + i] =
            (u32)(topN[i] & 0xFFFF) |
            ((u32)__half_as_ushort(__float2half_rn(wv)) << 16);
    }
}

// ---------------------------------------------------------------- diffusion hop (fp16, unrolled, packed kept)
__device__ __forceinline__ float4 hop_comb(float4 a, float4 f) {
    return make_float4((1.f - ALPHA) * a.x + ALPHA * f.x, (1.f - ALPHA) * a.y + ALPHA * f.y,
                       (1.f - ALPHA) * a.z + ALPHA * f.z, (1.f - ALPHA) * a.w + ALPHA * f.w);
}
__device__ __forceinline__ float4 elu_res(float4 r, float4 rs) {
    float x;
    x = r.x + rs.x; r.x = x > 0.f ? x : (expf(x) - 1.f);
    x = r.y + rs.y; r.y = x > 0.f ? x : (expf(x) - 1.f);
    x = r.z + rs.z; r.z = x > 0.f ? x : (expf(x) - 1.f);
    x = r.w + rs.w; r.w = x > 0.f ? x : (expf(x) - 1.f);
    return r;
}

// 512 threads = 32 nodes x 16 lanes; fixed-TOPK loop -> 10 gathers in flight.
// TAIL-GUARDED: last block covers nodes [nb, N_NODES) only.
template<bool FINAL>
__global__ __launch_bounds__(512) void hop_kernel(
        const __half* __restrict__ in16, const __half* __restrict__ feat16,
        const u32* __restrict__ kept,
        const float4* __restrict__ res, __half* __restrict__ out16,
        float4* __restrict__ out32) {
    __shared__ u32 lk[32 * HEADS * TOPK];
    int tb = threadIdx.x;
    int nb = blockIdx.x * 32;
    int nn = N_NODES - nb; if (nn > 32) nn = 32;       // valid nodes in this block
    int lmax = nn * HEADS * TOPK;
    for (int i = tb; i < lmax; i += 512) {
        lk[i] = kept[(size_t)nb * HEADS * TOPK + i];
    }
    __syncthreads();
    int nl = tb >> 4;
    if (nl >= nn) return;                               // tail guard (no syncs below)
    int c4 = tb & 15;
    int h  = c4 >> 2;
    int lbase = nl * HEADS * TOPK + h * TOPK;
    float4 acc = make_float4(0.f, 0.f, 0.f, 0.f);
    #pragma unroll
    for (int k = 0; k < TOPK; ++k) {
        u32 e = lk[lbase + k];
        int   s = (int)(e & 0xFFFF);
        float w = __half2float(__ushort_as_half((unsigned short)(e >> 16)));
        float4 v = load16(in16, (size_t)s * 16 + c4);
        acc.x += w * v.x; acc.y += w * v.y; acc.z += w * v.z; acc.w += w * v.w;
    }
    size_t o = (size_t)nb * 16 + tb;
    float4 f = load16(feat16, o);
    float4 r = hop_comb(acc, f);
    if (FINAL) {
        r = elu_res(r, res[o]);
        out32[o] = r;
    } else {
        store16(out16, o, r);
    }
}

// ---------------------------------------------------------------- launch
extern "C" void kernel_launch(void* const* d_in, const int* in_sizes, int n_in,
                              void* d_out, int out_size, void* d_ws, size_t ws_size,
                              hipStream_t stream) {
    (void)in_sizes; (void)n_in; (void)out_size; (void)ws_size;
    const float* ent_emb  = (const float*)d_in[0];
    const float* rel_emb  = (const float*)d_in[1];
    const int*   edge_src = (const int*)d_in[2];
    const int*   edge_dst = (const int*)d_in[3];
    const int*   edge_rel = (const int*)d_in[4];
    const float* W_ent    = (const float*)d_in[5];
    const float* W_rel    = (const float*)d_in[6];
    const float* attn_a   = (const float*)d_in[7];
    const float* res_W    = (const float*)d_in[8];
    const float* fc_rel_w = (const float*)d_in[9];

    char* wp = (char*)d_ws;
    auto alloc = [&](size_t bytes) -> void* {
        void* p = (void*)wp;
        wp += (bytes + 255) & ~(size_t)255;
        return p;
    };
    int*    bcur       = (int*)alloc((size_t)NBUCK * 4);
    int*    row_ptr    = (int*)alloc((size_t)(N_NODES + 1) * 4);
    u64*    staging    = (u64*)alloc((size_t)NBUCK * BUCK_CAP * 8);   // 8 MB
    u64*    sorted_pack= (u64*)alloc((size_t)N_EDGE * 8);             // 6.4 MB
    float*  s_src      = (float*)alloc((size_t)N_NODES * HEADS * 4);
    float*  s_dst      = (float*)alloc((size_t)N_NODES * HEADS * 4);
    float*  s_rel      = (float*)alloc((size_t)LAYERS * N_RELS * HEADS * 4);
    __half* feat16     = (__half*)alloc((size_t)N_NODES * HID * 2);
    __half* hcA16      = (__half*)alloc((size_t)N_NODES * HID * 2);
    __half* hcB16      = (__half*)alloc((size_t)N_NODES * HID * 2);
    float*  res        = (float*)alloc((size_t)N_NODES * HID * 4);
    u32*    kept       = (u32*)alloc((size_t)N_NODES * HEADS * TOPK * 4);  // 8 MB
    float*  sc_planes  = (float*)alloc((size_t)HEADS * N_EDGE * 4);        // 12.8 MB

    float* out_h = (float*)d_out;

    // upfront: rel projections for both layers + relout + bcur zero (no other deps)
    rel_all<<<3 * N_RELS, 64, 0, stream>>>(rel_emb, W_rel, attn_a, fc_rel_w,
                                           s_rel, out_h + (size_t)N_NODES * HID, bcur);
    // CSR by destination (layer-invariant, built once; l2 derives row_ptr itself)
    bucket_scatter_l1<<<L1_NBLK, 1024, 0, stream>>>(edge_src, edge_dst, edge_rel, bcur, staging);
    bucket_scatter_l2<<<NBUCK, 1024, 0, stream>>>(staging, bcur, row_ptr, sorted_pack);

    const float* h = ent_emb;
    const int nb_gemm = (N_NODES + 31) / 32;
    const dim3 gr_topk((N_NODES * 2 + 255) / 256, HEADS);   // 2 threads per dst, head in y
    const int nb_edge = (N_EDGE + 255) / 256;
    const int nb_hop  = (N_NODES + 31) / 32;   // 1563, 512-thread blocks (tail-guarded)

    for (int l = 0; l < LAYERS; ++l) {
        const float* We = W_ent + (size_t)l * HID * HID;
        const float* a  = attn_a + (size_t)l * 3 * HEADS * DH;
        const float* rW = res_W + (size_t)l * HID * HID;

        gemm_dual<<<nb_gemm, 256, 0, stream>>>(h, We, rW, a, feat16, res, s_src, s_dst, N_NODES);
        edge_scores<<<nb_edge, 256, 0, stream>>>(sorted_pack, s_src,
                                                 s_rel + (size_t)l * N_RELS * HEADS, sc_planes);
        topk_kernel<<<gr_topk, 256, 0, stream>>>(row_ptr, sorted_pack, sc_planes, s_dst, kept);
        hop_kernel<false><<<nb_hop, 512, 0, stream>>>(feat16, feat16, kept, nullptr, hcA16, nullptr);
        hop_kernel<false><<<nb_hop, 512, 0, stream>>>(hcA16, feat16, kept, nullptr, hcB16, nullptr);
        hop_kernel<true><<<nb_hop, 512, 0, stream>>>(hcB16, feat16, kept,
                                                     (const float4*)res, nullptr, (float4*)out_h);
        h = out_h;
    }
}

// Round 12
// 240.960 us; speedup vs baseline: 1.0190x; 1.0190x over previous
//
#include <hip/hip_runtime.h>
#include <hip/hip_fp16.h>
#include <math.h>

#define N_NODES 50000
#define N_RELS  500
#define N_EDGE  800000
#define HID     64
#define HEADS   4
#define DH      16
#define LAYERS  2
#define HOPS    3
#define TOPK    10
#define ALPHA   0.15f
#define SLOPE   0.2f

#define NBUCK 128
#define DST_PER_BUCK 391    // 128*391 = 50048 >= 50000
#define BUCK_CAP 8192       // mean 6256, sigma ~79 -> ~24 sigma margin
#define L1_EDGES 4096
#define L1_NBLK ((N_EDGE + L1_EDGES - 1) / L1_EDGES)   // 196

typedef unsigned long long u64;
typedef unsigned int u32;

// pack layout: [eid:20 (42..61) | dst:16 (26..41) | rel:10 (16..25) | src:16 (0..15)]
#define PK_SRC(p)  ((int)((p) & 0xFFFF))
#define PK_REL(p)  ((int)(((p) >> 16) & 0x3FF))
#define PK_DST(p)  ((int)(((p) >> 26) & 0xFFFF))
#define PK_EID(p)  ((int)((p) >> 42))

#define NEGI (-3.4e38f)

// monotone float -> u32 (order-preserving), and exact inverse
__device__ __forceinline__ unsigned ordf(float s) {
    unsigned u = __float_as_uint(s);
    return u ^ (0x80000000u | (unsigned)((int)u >> 31));
}
__device__ __forceinline__ float unordf(unsigned o) {
    unsigned u = (o & 0x80000000u) ? (o ^ 0x80000000u) : ~o;
    return __uint_as_float(u);
}

// fp16 row helpers: row = 64 halves (128 B); o4 indexes 8 B fp16 quads
__device__ __forceinline__ float4 load16(const __half* base, size_t o4) {
    float2 rv = *(const float2*)(base + o4 * 4);
    __half2 h0 = *(__half2*)&rv.x;
    __half2 h1 = *(__half2*)&rv.y;
    float2 f0 = __half22float2(h0);
    float2 f1 = __half22float2(h1);
    return make_float4(f0.x, f0.y, f1.x, f1.y);
}
__device__ __forceinline__ void store16(__half* base, size_t o4, float4 v) {
    __half2 h0 = __floats2half2_rn(v.x, v.y);
    __half2 h1 = __floats2half2_rn(v.z, v.w);
    float2 rv;
    *(__half2*)&rv.x = h0;
    *(__half2*)&rv.y = h1;
    *(float2*)(base + o4 * 4) = rv;
}

// ---------------------------------------------------------------- rel_all: relout + s_rel (both layers) + bcur zero
__global__ void rel_all(const float* __restrict__ rel_emb, const float* __restrict__ W_rel,
                        const float* __restrict__ attn_a, const float* __restrict__ fc_rel_w,
                        float* __restrict__ s_rel, float* __restrict__ out_hr,
                        int* __restrict__ bcur) {
    __shared__ float proj[64];
    int b = blockIdx.x, c = threadIdx.x;   // 1500 x 64
    if (b == 0) for (int i = c; i < NBUCK; i += 64) bcur[i] = 0;
    int mode = b / N_RELS;                 // 0=relout, 1=layer0 s_rel, 2=layer1 s_rel
    int r = b - mode * N_RELS;
    const float* W = (mode == 0) ? fc_rel_w : (W_rel + (size_t)(mode - 1) * HID * HID);
    float acc = 0.f;
    #pragma unroll
    for (int k = 0; k < 64; ++k) acc += rel_emb[(size_t)r * 64 + k] * W[k * 64 + c];
    if (mode == 0) { out_hr[(size_t)r * 64 + c] = acc; return; }
    proj[c] = acc;
    __syncthreads();
    if (c < HEADS) {
        const float* a2 = attn_a + (size_t)(mode - 1) * 3 * HEADS * DH + 2 * HEADS * DH;
        float s = 0.f;
        #pragma unroll
        for (int d = 0; d < 16; ++d) s += proj[c * 16 + d] * a2[c * 16 + d];
        s_rel[(size_t)(mode - 1) * N_RELS * HEADS + r * HEADS + c] = s;
    }
}

// ---------------------------------------------------------------- level-1: bucket stage (no global hist)
__global__ __launch_bounds__(1024) void bucket_scatter_l1(
        const int* __restrict__ src, const int* __restrict__ dst, const int* __restrict__ rel,
        int* __restrict__ bcur, u64* __restrict__ staging) {
    __shared__ u64 buf[L1_EDGES];
    __shared__ unsigned char bb[L1_EDGES];
    __shared__ int hist[NBUCK], lstart[NBUCK], cur[NBUCK], delta[NBUCK];
    __shared__ int wtot[2];
    int t = threadIdx.x;
    int e0 = blockIdx.x * L1_EDGES;
    if (t < NBUCK) hist[t] = 0;
    __syncthreads();

    u64 myp[4]; int myb[4]; bool mv[4];
    #pragma unroll
    for (int q = 0; q < 4; ++q) {
        int e = e0 + q * 1024 + t;
        mv[q] = (e < N_EDGE);
        if (mv[q]) {
            int d = dst[e];
            int b = d / DST_PER_BUCK;
            myp[q] = ((u64)(unsigned)e << 42) | ((u64)(unsigned)d << 26)
                   | ((unsigned)rel[e] << 16) | (unsigned)src[e];
            myb[q] = b;
            atomicAdd(&hist[b], 1);
        }
    }
    __syncthreads();
    int inc = 0;
    if (t < NBUCK) {       // two-wave exclusive scan over 128 hist entries
        int v = hist[t];
        int lane = t & 63;
        inc = v;
        #pragma unroll
        for (int off = 1; off < 64; off <<= 1) {
            int u = __shfl_up(inc, off, 64);
            if (lane >= off) inc += u;
        }
        if (lane == 63) wtot[t >> 6] = inc;
    }
    __syncthreads();
    if (t < NBUCK) {
        int base = (t >= 64) ? wtot[0] : 0;
        int excl = base + inc - hist[t];
        lstart[t] = excl;
        cur[t] = excl;
    }
    __syncthreads();
    #pragma unroll
    for (int q = 0; q < 4; ++q) {
        if (mv[q]) {
            int lp = atomicAdd(&cur[myb[q]], 1);
            buf[lp] = myp[q];
            bb[lp] = (unsigned char)myb[q];
        }
    }
    __syncthreads();
    if (t < NBUCK && hist[t] > 0) {
        int g = atomicAdd(&bcur[t], hist[t]);
        delta[t] = t * BUCK_CAP + g - lstart[t];
    }
    __syncthreads();
    int total = N_EDGE - e0; if (total > L1_EDGES) total = L1_EDGES;
    for (int i = t; i < total; i += 1024) {
        staging[(size_t)(delta[bb[i]] + i)] = buf[i];
    }
}

// ---------------------------------------------------------------- level-2: per-bucket hist + scan + row_ptr + place
__global__ __launch_bounds__(1024) void bucket_scatter_l2(
        const u64* __restrict__ staging, const int* __restrict__ bcur,
        int* __restrict__ row_ptr, u64* __restrict__ sorted_pack) {
    __shared__ int hist[DST_PER_BUCK];
    __shared__ int cur[DST_PER_BUCK];
    __shared__ int sc[512];
    __shared__ int base_sh;
    int b = blockIdx.x, t = threadIdx.x;
    int d0 = b * DST_PER_BUCK;
    int d1 = d0 + DST_PER_BUCK; if (d1 > N_NODES) d1 = N_NODES;
    int nd = d1 - d0;
    if (t < DST_PER_BUCK) hist[t] = 0;
    if (t < 64) {          // base = sum bcur[0..b-1]
        int s = 0;
        if (t < b) s += bcur[t];
        if (t + 64 < b) s += bcur[t + 64];
        #pragma unroll
        for (int off = 32; off > 0; off >>= 1) s += __shfl_down(s, off, 64);
        if (t == 0) base_sh = s;
    }
    int cnt_b = bcur[b];
    size_t sbase = (size_t)b * BUCK_CAP;
    __syncthreads();
    for (int j = t; j < cnt_b; j += 1024) {              // pass 1: histogram
        u64 p = staging[sbase + j];
        atomicAdd(&hist[PK_DST(p) - d0], 1);
    }
    __syncthreads();
    if (t < 512) sc[t] = (t < nd) ? hist[t] : 0;
    __syncthreads();
    #pragma unroll
    for (int off = 1; off < 512; off <<= 1) {            // Hillis-Steele inclusive scan
        int v = (t < 512 && t >= off) ? sc[t - off] : 0;
        __syncthreads();
        if (t < 512) sc[t] += v;
        __syncthreads();
    }
    if (t < nd) {
        int excl = base_sh + sc[t] - hist[t];
        cur[t] = excl;
        row_ptr[d0 + t] = excl;
    }
    if (b == NBUCK - 1 && t == 0) row_ptr[N_NODES] = N_EDGE;
    __syncthreads();
    for (int j = t; j < cnt_b; j += 1024) {              // pass 2: place (L2-hot)
        u64 p = staging[sbase + j];
        int pos = atomicAdd(&cur[PK_DST(p) - d0], 1);
        sorted_pack[pos] = p;
    }
}

// ---------------------------------------------------------------- dense: dual GEMM + score epilogue
__global__ __launch_bounds__(256) void gemm_dual(
        const float* __restrict__ A, const float* __restrict__ W1, const float* __restrict__ W2,
        const float* __restrict__ a_vec,
        __half* __restrict__ C1h, float* __restrict__ C2,
        float* __restrict__ s_src, float* __restrict__ s_dst, int n) {
    __shared__ float W1s[64][64];   // [k][c]
    __shared__ float W2s[64][64];
    __shared__ float As[32][64];
    __shared__ float a_sh[128];
    int t = threadIdx.x;      // 256
    const float4* W1v = (const float4*)W1;
    const float4* W2v = (const float4*)W2;
    for (int i = t; i < 1024; i += 256) {
        ((float4*)W1s)[i] = W1v[i];
        ((float4*)W2s)[i] = W2v[i];
    }
    if (t < 128) a_sh[t] = a_vec[t];
    int row0 = blockIdx.x * 32;
    const float4* Av = (const float4*)A;
    for (int i = t; i < 512; i += 256) {
        int gr = row0 + (i >> 4);
        ((float4*)As)[i] = (gr < n) ? Av[(size_t)row0 * 16 + i] : make_float4(0.f, 0.f, 0.f, 0.f);
    }
    __syncthreads();
    int cq = (t & 15) * 4;
    int rs = t >> 4;
    float4 a1a = make_float4(0.f,0.f,0.f,0.f), a1b = a1a, a2a = a1a, a2b = a1a;
    #pragma unroll 4
    for (int k = 0; k < 64; ++k) {
        float va = As[rs][k];
        float vb = As[rs + 16][k];
        float4 w1 = *(const float4*)&W1s[k][cq];
        float4 w2 = *(const float4*)&W2s[k][cq];
        a1a.x += va * w1.x; a1a.y += va * w1.y; a1a.z += va * w1.z; a1a.w += va * w1.w;
        a2a.x += va * w2.x; a2a.y += va * w2.y; a2a.z += va * w2.z; a2a.w += va * w2.w;
        a1b.x += vb * w1.x; a1b.y += vb * w1.y; a1b.z += vb * w1.z; a1b.w += vb * w1.w;
        a2b.x += vb * w2.x; a2b.y += vb * w2.y; a2b.z += vb * w2.z; a2b.w += vb * w2.w;
    }
    int gra = row0 + rs, grb = row0 + rs + 16;
    if (gra < n) {
        store16(C1h, (size_t)gra * 16 + (t & 15), a1a);
        *(float4*)&C2[(size_t)gra * 64 + cq] = a2a;
    }
    if (grb < n) {
        store16(C1h, (size_t)grb * 16 + (t & 15), a1b);
        *(float4*)&C2[(size_t)grb * 64 + cq] = a2b;
    }
    __syncthreads();
    *(float4*)&As[rs][cq]      = a1a;      // park fp32 C1 tile for score epilogue
    *(float4*)&As[rs + 16][cq] = a1b;
    __syncthreads();
    if (t < 128) {
        int nl = t >> 2, h = t & 3;
        int gr = row0 + nl;
        if (gr < n) {
            float ss = 0.f, sd = 0.f;
            #pragma unroll
            for (int d = 0; d < 16; ++d) {
                float v = As[nl][h * 16 + d];
                ss += v * a_sh[h * 16 + d];
                sd += v * a_sh[64 + h * 16 + d];
            }
            s_src[gr * 4 + h] = ss;
            s_dst[gr * 4 + h] = sd;
        }
    }
}

// ---------------------------------------------------------------- edge scores (head-major planes)
__global__ void edge_scores(const u64* __restrict__ pack, const float* __restrict__ s_src,
                            const float* __restrict__ s_rel, float* __restrict__ sc) {
    int j = blockIdx.x * 256 + threadIdx.x;
    if (j >= N_EDGE) return;
    u64 p = pack[j];
    int src = PK_SRC(p);
    int rel = PK_REL(p);
    float4 a = *(const float4*)(s_src + (size_t)src * 4);
    float4 b = *(const float4*)(s_rel + (size_t)rel * 4);
    sc[0 * N_EDGE + j] = a.x + b.x;
    sc[1 * N_EDGE + j] = a.y + b.y;
    sc[2 * N_EDGE + j] = a.z + b.z;
    sc[3 * N_EDGE + j] = a.w + b.w;
}

// ---------------------------------------------------------------- top-k (u64-key, 2 threads per (dst,head))
// selects on RAW sc; key = [ord(score):32 | (0xFFFFF - eid):20] -> score desc, eid asc.
// output: packed u32 [fp16 w | u16 src]; padded slots have w=0.
__global__ void topk_kernel(const int* __restrict__ row_ptr, const u64* __restrict__ pack,
                            const float* __restrict__ sc_all, const float* __restrict__ s_dst,
                            u32* __restrict__ kept) {
    int tid = blockIdx.x * 256 + threadIdx.x;
    int t = tid >> 1;                 // (dst,head) pair index
    if (t >= N_NODES * HEADS) return;
    int q = tid & 1;                  // which half of the segment
    int d = t >> 2, h = t & 3;
    int beg = row_ptr[d], end = row_ptr[d + 1];
    const float* sc = sc_all + (size_t)h * N_EDGE;

    u64 topK[TOPK]; int topN[TOPK];
    #pragma unroll
    for (int i = 0; i < TOPK; ++i) { topK[i] = 0ull; topN[i] = 0; }
    float thr9 = unordf(0u);   // -NaN: comparisons false -> nothing rejected while filling

    auto ins = [&](float s, int j) {
        if (s < thr9) return;                       // NaN-safe: false while unfilled
        u64 p = pack[j];
        unsigned eid = (unsigned)PK_EID(p);
        u64 key = ((u64)ordf(s) << 20) | (u64)(0xFFFFFu - eid);
        if (key <= topK[TOPK - 1]) return;
        int sn = PK_SRC(p);
        #pragma unroll
        for (int i = 0; i < TOPK; ++i) {
            bool b = key > topK[i];
            u64 tk = topK[i]; int tn = topN[i];
            topK[i] = b ? key : tk;  topN[i] = b ? sn : tn;
            key     = b ? tk : key;  sn      = b ? tn : sn;
        }
        thr9 = unordf((unsigned)(topK[TOPK - 1] >> 20));
    };

    for (int j = (beg & ~3) + (q << 2); j < end; j += 8) {   // interleaved aligned batches
        float4 v = *(const float4*)(sc + j);
        float s0 = (j     >= beg)                ? v.x : NEGI;
        float s1 = (j + 1 >= beg && j + 1 < end) ? v.y : NEGI;
        float s2 = (j + 2 >= beg && j + 2 < end) ? v.z : NEGI;
        float s3 = (j + 3 < end)                 ? v.w : NEGI;
        float mx = fmaxf(fmaxf(s0, s1), fmaxf(s2, s3));
        if (mx < thr9) continue;
        ins(s0, j); ins(s1, j + 1); ins(s2, j + 2); ins(s3, j + 3);
    }

    // merge partner's sorted list (adjacent lane, disjoint edges -> distinct keys)
    u64 ok[TOPK]; int on[TOPK];
    #pragma unroll
    for (int i = 0; i < TOPK; ++i) {
        unsigned lo = (unsigned)__shfl_xor((int)(topK[i] & 0xFFFFFFFFull), 1, 64);
        unsigned hi = (unsigned)__shfl_xor((int)(topK[i] >> 32), 1, 64);
        ok[i] = ((u64)hi << 32) | lo;
        on[i] = __shfl_xor(topN[i], 1, 64);
    }
    for (int i = 0; i < TOPK; ++i) {
        u64 key = ok[i]; int sn = on[i];
        if (key <= topK[TOPK - 1]) break;          // rest are smaller: can't enter top-10
        #pragma unroll
        for (int ii = 0; ii < TOPK; ++ii) {
            bool b = key > topK[ii];
            u64 tk = topK[ii]; int tn = topN[ii];
            topK[ii] = b ? key : tk;  topN[ii] = b ? sn : tn;
            key      = b ? tk : key;  sn       = b ? tn : sn;
        }
    }
    if (q) return;                                 // both lanes hold identical merged lists

    int deg = end - beg;
    int cnt = deg < TOPK ? deg : TOPK;
    float sdst = s_dst[t];
    float tm = unordf((unsigned)(topK[0] >> 20)) + sdst;
    tm = tm > 0.f ? tm : SLOPE * tm;
    float w[TOPK]; float den = 0.f;
    #pragma unroll
    for (int i = 0; i < TOPK; ++i) {
        float ti = unordf((unsigned)(topK[i] >> 20)) + sdst;
        ti = ti > 0.f ? ti : SLOPE * ti;
        float e = (i < cnt) ? expf(ti - tm) : 0.f;
        w[i] = e; den += e;
    }
    float inv = 1.f / (den + 1e-16f);
    #pragma unroll
    for (int i = 0; i < TOPK; ++i) {
        float wv = (i < cnt) ? w[i] * inv : 0.f;
        kept[(size_t)t * TOPK + i] =
            (u32)(topN[i] & 0xFFFF) |
            ((u32)__half_as_ushort(__float2half_rn(wv)) << 16);
    }
}

// ---------------------------------------------------------------- diffusion hop (fp16, unrolled, packed kept)
__device__ __forceinline__ float4 hop_comb(float4 a, float4 f) {
    return make_float4((1.f - ALPHA) * a.x + ALPHA * f.x, (1.f - ALPHA) * a.y + ALPHA * f.y,
                       (1.f - ALPHA) * a.z + ALPHA * f.z, (1.f - ALPHA) * a.w + ALPHA * f.w);
}
__device__ __forceinline__ float4 elu_res(float4 r, float4 rs) {
    float x;
    x = r.x + rs.x; r.x = x > 0.f ? x : (expf(x) - 1.f);
    x = r.y + rs.y; r.y = x > 0.f ? x : (expf(x) - 1.f);
    x = r.z + rs.z; r.z = x > 0.f ? x : (expf(x) - 1.f);
    x = r.w + rs.w; r.w = x > 0.f ? x : (expf(x) - 1.f);
    return r;
}

// 256 threads = 16 nodes x 16 lanes; fixed-TOPK loop -> 10 gathers in flight
template<bool FINAL>
__global__ void hop_kernel(const __half* __restrict__ in16, const __half* __restrict__ feat16,
                           const u32* __restrict__ kept,
                           const float4* __restrict__ res, __half* __restrict__ out16,
                           float4* __restrict__ out32) {
    __shared__ u32 lk[16 * HEADS * TOPK];
    int tb = threadIdx.x;
    int nb = blockIdx.x * 16;
    for (int i = tb; i < 16 * HEADS * TOPK; i += 256) {
        lk[i] = kept[(size_t)nb * HEADS * TOPK + i];
    }
    __syncthreads();
    int nl = tb >> 4;
    int c4 = tb & 15;
    int h  = c4 >> 2;
    int lbase = nl * HEADS * TOPK + h * TOPK;
    float4 acc = make_float4(0.f, 0.f, 0.f, 0.f);
    #pragma unroll
    for (int k = 0; k < TOPK; ++k) {
        u32 e = lk[lbase + k];
        int   s = (int)(e & 0xFFFF);
        float w = __half2float(__ushort_as_half((unsigned short)(e >> 16)));
        float4 v = load16(in16, (size_t)s * 16 + c4);
        acc.x += w * v.x; acc.y += w * v.y; acc.z += w * v.z; acc.w += w * v.w;
    }
    size_t o = (size_t)nb * 16 + tb;
    float4 f = load16(feat16, o);
    float4 r = hop_comb(acc, f);
    if (FINAL) {
        r = elu_res(r, res[o]);
        out32[o] = r;
    } else {
        store16(out16, o, r);
    }
}

// ---------------------------------------------------------------- launch
extern "C" void kernel_launch(void* const* d_in, const int* in_sizes, int n_in,
                              void* d_out, int out_size, void* d_ws, size_t ws_size,
                              hipStream_t stream) {
    (void)in_sizes; (void)n_in; (void)out_size; (void)ws_size;
    const float* ent_emb  = (const float*)d_in[0];
    const float* rel_emb  = (const float*)d_in[1];
    const int*   edge_src = (const int*)d_in[2];
    const int*   edge_dst = (const int*)d_in[3];
    const int*   edge_rel = (const int*)d_in[4];
    const float* W_ent    = (const float*)d_in[5];
    const float* W_rel    = (const float*)d_in[6];
    const float* attn_a   = (const float*)d_in[7];
    const float* res_W    = (const float*)d_in[8];
    const float* fc_rel_w = (const float*)d_in[9];

    char* wp = (char*)d_ws;
    auto alloc = [&](size_t bytes) -> void* {
        void* p = (void*)wp;
        wp += (bytes + 255) & ~(size_t)255;
        return p;
    };
    int*    bcur       = (int*)alloc((size_t)NBUCK * 4);
    int*    row_ptr    = (int*)alloc((size_t)(N_NODES + 1) * 4);
    u64*    staging    = (u64*)alloc((size_t)NBUCK * BUCK_CAP * 8);   // 8 MB
    u64*    sorted_pack= (u64*)alloc((size_t)N_EDGE * 8);             // 6.4 MB
    float*  s_src      = (float*)alloc((size_t)N_NODES * HEADS * 4);
    float*  s_dst      = (float*)alloc((size_t)N_NODES * HEADS * 4);
    float*  s_rel      = (float*)alloc((size_t)LAYERS * N_RELS * HEADS * 4);
    __half* feat16     = (__half*)alloc((size_t)N_NODES * HID * 2);
    __half* hcA16      = (__half*)alloc((size_t)N_NODES * HID * 2);
    __half* hcB16      = (__half*)alloc((size_t)N_NODES * HID * 2);
    float*  res        = (float*)alloc((size_t)N_NODES * HID * 4);
    u32*    kept       = (u32*)alloc((size_t)N_NODES * HEADS * TOPK * 4);  // 8 MB
    float*  sc_planes  = (float*)alloc((size_t)HEADS * N_EDGE * 4);        // 12.8 MB

    float* out_h = (float*)d_out;

    // upfront: rel projections for both layers + relout + bcur zero (no other deps)
    rel_all<<<3 * N_RELS, 64, 0, stream>>>(rel_emb, W_rel, attn_a, fc_rel_w,
                                           s_rel, out_h + (size_t)N_NODES * HID, bcur);
    // CSR by destination (layer-invariant, built once; l2 derives row_ptr itself)
    bucket_scatter_l1<<<L1_NBLK, 1024, 0, stream>>>(edge_src, edge_dst, edge_rel, bcur, staging);
    bucket_scatter_l2<<<NBUCK, 1024, 0, stream>>>(staging, bcur, row_ptr, sorted_pack);

    const float* h = ent_emb;
    const int nb_gemm = (N_NODES + 31) / 32;
    const int nb_topk = (N_NODES * HEADS * 2 + 255) / 256;   // 2 threads per (dst,head)
    const int nb_edge = (N_EDGE + 255) / 256;
    const int nb_hop  = N_NODES / 16;   // 3125

    for (int l = 0; l < LAYERS; ++l) {
        const float* We = W_ent + (size_t)l * HID * HID;
        const float* a  = attn_a + (size_t)l * 3 * HEADS * DH;
        const float* rW = res_W + (size_t)l * HID * HID;

        gemm_dual<<<nb_gemm, 256, 0, stream>>>(h, We, rW, a, feat16, res, s_src, s_dst, N_NODES);
        edge_scores<<<nb_edge, 256, 0, stream>>>(sorted_pack, s_src,
                                                 s_rel + (size_t)l * N_RELS * HEADS, sc_planes);
        topk_kernel<<<nb_topk, 256, 0, stream>>>(row_ptr, sorted_pack, sc_planes, s_dst, kept);
        hop_kernel<false><<<nb_hop, 256, 0, stream>>>(feat16, feat16, kept, nullptr, hcA16, nullptr);
        hop_kernel<false><<<nb_hop, 256, 0, stream>>>(hcA16, feat16, kept, nullptr, hcB16, nullptr);
        hop_kernel<true><<<nb_hop, 256, 0, stream>>>(hcB16, feat16, kept,
                                                     (const float4*)res, nullptr, (float4*)out_h);
        h = out_h;
    }
}